// Round 7
// baseline (198.807 us; speedup 1.0000x reference)
//
#include <hip/hip_runtime.h>
#include <math.h>

#define HH 160
#define WW 160
#define DD 160
#define VOL (HH*WW*DD)          // 4,096,000
#define KS 11
#define PAD 5
#define NBATCH 2
#define NTOT (NBATCH*VOL)

// fused tile geometry
#define WT 16                    // w outputs per block
#define DT 16                    // d outputs per block
#define HT 32                    // h outputs per block (delay-line walk)
#define WPN (WT + 2*PAD)         // 26 w rows incl. halo
#define NSTEP (HT + 2*PAD)       // 42
// LDS strides (words) — bank-audited
#define RS 74                    // raw row (r6-proven: max 3-way)
#define P01S 38                  // plane row (r6-proven writes; reads 2-way)
#define P4S 17                   // c4 plane: phase2 reads 16w+d would be 8-way at 16; 17 -> 2-way
#define RAW_W (WPN*RS)           // 1924 words per raw buffer
#define P01_W (WPN*P01S)         // 988
#define P4_W  (WPN*P4S)          // 442

typedef float v2f __attribute__((ext_vector_type(2)));
typedef float v4f __attribute__((ext_vector_type(4)));

struct Wts { float w[KS]; };

__device__ __forceinline__ int mirror(int i, int n) {
    if (i < 0) i = -i;
    if (i >= n) i = 2*n - 2 - i;
    return i;
}

// tied VOP3P asm (phase1): in-place accumulate, no result-copy movs
__device__ __forceinline__ void pk_fma_acc(v2f& c, v2f a, v2f b) {
    asm("v_pk_fma_f32 %0, %1, %2, %0" : "+v"(c) : "v"(a), "v"(b));
}
__device__ __forceinline__ void pk_add_acc(v2f& c, v2f a) {
    asm("v_pk_add_f32 %0, %0, %1" : "+v"(c) : "v"(a));
}
__device__ __forceinline__ v2f pk_mul(v2f a, v2f b) {
    v2f d; asm("v_pk_mul_f32 %0, %1, %2" : "=v"(d) : "v"(a), "v"(b)); return d;
}

// DPP W-blur taps (phase2): acc += wt * shifted(src) within a row of 16 lanes.
// OOB lanes contribute 0 under either BOUND_CTRL semantics (zero-fill or
// skip-write) since the op is an accumulate.
#define FMAC_SHR(acc, src, wt, JSTR) \
    asm("v_fmac_f32 %0, %1, %2 row_shr:" JSTR " bound_ctrl:0" \
        : "+v"(acc) : "v"(src), "v"(wt))
#define FMAC_SHL(acc, src, wt, KSTR) \
    asm("v_fmac_f32 %0, %1, %2 row_shl:" KSTR " bound_ctrl:0" \
        : "+v"(acc) : "v"(src), "v"(wt))
// one tap j (1..10): vlo part from row_shr:j, vhi part from row_shl:16-j
#define WTAP(J, K) do { \
    FMAC_SHR(b0, lo0, wv[J], #J); FMAC_SHL(b0, hi0, wv[J], #K); \
    FMAC_SHR(b1, lo1, wv[J], #J); FMAC_SHL(b1, hi1, wv[J], #K); \
    FMAC_SHR(b2, lo2, wv[J], #J); FMAC_SHL(b2, hi2, wv[J], #K); \
    FMAC_SHR(b3, lo3, wv[J], #J); FMAC_SHL(b3, hi3, wv[J], #K); \
    FMAC_SHR(b4, lo4, wv[J], #J); FMAC_SHL(b4, hi4, wv[J], #K); \
} while (0)

__global__ void init_out(float* out) {
    if (threadIdx.x == 0 && blockIdx.x == 0) out[0] = 1.0f;
}

// Fully fused 3D SSIM.
// Round-7: phase2 W-blur moved from LDS re-reads (11 taps x 20B = 220B/thr/step,
// the dominant LDS-bandwidth term) to DPP register shifts: each plane point is
// read ONCE (40B), taps come from row_shr/row_shl cross-lane fmacs.
__global__ __launch_bounds__(256) void fused(const float* __restrict__ src,
                                             const float* __restrict__ ref,
                                             float* __restrict__ out,
                                             Wts wts, float scale) {
    __shared__ __align__(16) float raw [2*RAW_W];   // (s,r) interleaved window
    __shared__ __align__(16) float pl01[2*P01_W];   // (mu1,mu2)
    __shared__ __align__(16) float pl23[2*P01_W];   // (m11,m22)
    __shared__ __align__(16) float pl4 [2*P4_W];    // m12

    const int bx  = blockIdx.x;
    const int dt_ = bx % (DD/DT);
    const int wt_ = (bx / (DD/DT)) % (WW/WT);
    const int ht_ = (bx / ((DD/DT)*(WW/WT))) % (HH/HT);
    const int b   = bx / ((DD/DT)*(WW/WT)*(HH/HT));
    const int d0 = dt_*DT, w0 = wt_*WT, h0 = ht_*HT;

    // aligned 32-float raw window [dbase, dbase+32) covers all mirrored d-taps
    const int  dbase = (d0 == 0) ? 0 : ((d0 == DD-DT) ? DD-32 : d0-8);
    const bool dedge = (d0 == 0) || (d0 == DD-DT);

    const int tid = threadIdx.x;
    const float* __restrict__ sp = src + (size_t)b*VOL;
    const float* __restrict__ rp = ref + (size_t)b*VOL;

    // ---- stage identity: 208 threads, (row swp, quad sq) ----
    const bool sact = (tid < WPN*8);                 // 208: stage AND phase1
    const int  swp = tid >> 3, sq = tid & 7;
    const int  sgoff  = mirror(w0 - PAD + (sact ? swp : 0), WW)*DD + dbase + sq*4;
    const int  srawof = swp*RS + sq*8;

    // ---- phase1 identity: thread (p_wp, p_dlp) owns points d=2dlp, 2dlp+1 ----
    const int  p_wp  = tid >> 3;                     // 0..25
    const int  p_dlp = tid & 7;                      // 0..7
    const int  pA01  = p_wp*P01S + 4*p_dlp;          // (wp, 2dlp) in c01/c23
    const int  pA4   = p_wp*P4S  + 2*p_dlp;          // (wp, 2dlp) in c4
    const int  p_rbase = p_wp*RS + 6 + 4*p_dlp;      // interior tap base

    // edge-block mirrored d-tap offsets (12-tap union window), hoisted
    int eoff[12];
    if (dedge) {
#pragma unroll
        for (int j = 0; j < 12; ++j)
            eoff[j] = 2*(mirror(d0 + 2*p_dlp - PAD + j, DD) - dbase);
    }

    // ---- phase2 identity: output (w0 + w2, d0 + d2); w2 = DPP row lane ----
    const int w2 = tid & 15;                         // w within tile (row of 16)
    const int d2 = tid >> 4;                         // d within tile
    const int vhiRow   = (w2 + 16 <= 25) ? (w2 + 16) : 25;  // clamp: rows >25 unused
    const int vloB01   = w2*P01S + 2*d2;
    const int vhiB01   = vhiRow*P01S + 2*d2;
    const int vloB4    = w2*P4S + d2;
    const int vhiB4    = vhiRow*P4S + d2;

    // packed weights (phase1) + scalar VGPR weights (phase2 DPP src1 must be VGPR)
    v2f wpk[KS];
#pragma unroll
    for (int k = 0; k < KS; ++k) { wpk[k].x = wts.w[k]; wpk[k].y = wts.w[k]; }
    float wv[KS];
#pragma unroll
    for (int k = 0; k < KS; ++k) { wv[k] = wts.w[k]; asm("" : "+v"(wv[k])); }

    float acc[5][KS];                                // H delay-line ring (scalar)
#pragma unroll
    for (int c = 0; c < 5; ++c)
#pragma unroll
        for (int s = 0; s < KS; ++s) acc[c][s] = 0.f;

    // ---- prologue: stage step 0 into raw half 0, prefetch step 1 ----
    v4f ra = (v4f)0.f, rb_ = (v4f)0.f;
    if (sact) {
        const size_t o0 = (size_t)mirror(h0 - PAD, HH)*(WW*DD) + sgoff;
        ra  = *reinterpret_cast<const v4f*>(sp + o0);
        rb_ = *reinterpret_cast<const v4f*>(rp + o0);
        v2f p0, p1, p2, p3;
        p0.x=ra.x; p0.y=rb_.x;  p1.x=ra.y; p1.y=rb_.y;
        p2.x=ra.z; p2.y=rb_.z;  p3.x=ra.w; p3.y=rb_.w;
        *reinterpret_cast<v2f*>(&raw[srawof])     = p0;
        *reinterpret_cast<v2f*>(&raw[srawof + 2]) = p1;
        *reinterpret_cast<v2f*>(&raw[srawof + 4]) = p2;
        *reinterpret_cast<v2f*>(&raw[srawof + 6]) = p3;
        const size_t o1 = (size_t)mirror(h0 - PAD + 1, HH)*(WW*DD) + sgoff;
        ra  = *reinterpret_cast<const v4f*>(sp + o1);
        rb_ = *reinterpret_cast<const v4f*>(rp + o1);
    }
    __syncthreads();

    float ssum = 0.f;
    int rawRd = 0, rawWr = RAW_W, po01 = 0, po4 = 0;

#pragma unroll 1
    for (int tb = 0; tb < 44; tb += 11) {
#pragma unroll
        for (int ts = 0; ts < 11; ++ts) {
            const int t = tb + ts;
            if (t < NSTEP) {                     // block-uniform
                if (sact) {
                    // ---- A: stage step t+1 (prefetched regs) -> raw[rawWr] ----
                    v2f p0, p1, p2, p3;
                    p0.x=ra.x; p0.y=rb_.x;  p1.x=ra.y; p1.y=rb_.y;
                    p2.x=ra.z; p2.y=rb_.z;  p3.x=ra.w; p3.y=rb_.w;
                    *reinterpret_cast<v2f*>(&raw[rawWr + srawof])     = p0;
                    *reinterpret_cast<v2f*>(&raw[rawWr + srawof + 2]) = p1;
                    *reinterpret_cast<v2f*>(&raw[rawWr + srawof + 4]) = p2;
                    *reinterpret_cast<v2f*>(&raw[rawWr + srawof + 6]) = p3;
                    // ---- B: re-issue prefetch for step t+2 ----
                    const size_t on = (size_t)mirror(h0 - PAD + t + 2, HH)*(WW*DD) + sgoff;
                    ra  = *reinterpret_cast<const v4f*>(sp + on);
                    rb_ = *reinterpret_cast<const v4f*>(rp + on);

                    // ---- C: phase1(t): D-blur for d-pair -> planes ----
                    v2f muA=(v2f)0.f, mmA=(v2f)0.f, muB=(v2f)0.f, mmB=(v2f)0.f;
                    float m12A=0.f, m12B=0.f;
                    if (!dedge) {
                        const float* r0 = &raw[rawRd + p_rbase];
#pragma unroll
                        for (int j = 0; j < 12; ++j) {
                            v2f sr = *reinterpret_cast<const v2f*>(r0 + 2*j);
                            if (j < 11) {
                                v2f p = pk_mul(sr, wpk[j]);
                                pk_add_acc(muA, p);
                                pk_fma_acc(mmA, p, sr);
                                m12A = fmaf(p.x, sr.y, m12A);
                            }
                            if (j > 0) {
                                v2f p = pk_mul(sr, wpk[j-1]);
                                pk_add_acc(muB, p);
                                pk_fma_acc(mmB, p, sr);
                                m12B = fmaf(p.x, sr.y, m12B);
                            }
                        }
                    } else {
                        const float* r0 = &raw[rawRd + p_wp*RS];
#pragma unroll
                        for (int j = 0; j < 12; ++j) {
                            v2f sr = *reinterpret_cast<const v2f*>(r0 + eoff[j]);
                            if (j < 11) {
                                v2f p = pk_mul(sr, wpk[j]);
                                pk_add_acc(muA, p);
                                pk_fma_acc(mmA, p, sr);
                                m12A = fmaf(p.x, sr.y, m12A);
                            }
                            if (j > 0) {
                                v2f p = pk_mul(sr, wpk[j-1]);
                                pk_add_acc(muB, p);
                                pk_fma_acc(mmB, p, sr);
                                m12B = fmaf(p.x, sr.y, m12B);
                            }
                        }
                    }
                    *reinterpret_cast<v2f*>(&pl01[po01 + pA01])     = muA;
                    *reinterpret_cast<v2f*>(&pl01[po01 + pA01 + 2]) = muB;
                    *reinterpret_cast<v2f*>(&pl23[po01 + pA01])     = mmA;
                    *reinterpret_cast<v2f*>(&pl23[po01 + pA01 + 2]) = mmB;
                    pl4[po4 + pA4]     = m12A;       // P4S odd: 2x b32
                    pl4[po4 + pA4 + 1] = m12B;
                }

                __syncthreads();                 // the ONLY barrier per step

                // ---- E: phase2(t): read each plane point ONCE, DPP W-blur,
                //         H-ring + SSIM ----
                {
                    float lo0 = pl01[po01 + vloB01], lo1 = pl01[po01 + vloB01 + 1];
                    float lo2 = pl23[po01 + vloB01], lo3 = pl23[po01 + vloB01 + 1];
                    float lo4 = pl4 [po4  + vloB4];
                    float hi0 = pl01[po01 + vhiB01], hi1 = pl01[po01 + vhiB01 + 1];
                    float hi2 = pl23[po01 + vhiB01], hi3 = pl23[po01 + vhiB01 + 1];
                    float hi4 = pl4 [po4  + vhiB4];

                    // tap j=0: own vlo (no shift); taps 1..10: DPP two-shift
                    float b0 = wv[0]*lo0, b1 = wv[0]*lo1, b2 = wv[0]*lo2,
                          b3 = wv[0]*lo3, b4 = wv[0]*lo4;
                    WTAP(1, 15); WTAP(2, 14); WTAP(3, 13); WTAP(4, 12);
                    WTAP(5, 11); WTAP(6, 10); WTAP(7, 9);  WTAP(8, 8);
                    WTAP(9, 7);  WTAP(10, 6);

#pragma unroll
                    for (int m = 0; m < 11; ++m) {
                        const int slot = (ts + m) % 11;   // static after unroll
                        const float wt = wts.w[10 - m];
                        acc[0][slot] = fmaf(wt, b0, acc[0][slot]);
                        acc[1][slot] = fmaf(wt, b1, acc[1][slot]);
                        acc[2][slot] = fmaf(wt, b2, acc[2][slot]);
                        acc[3][slot] = fmaf(wt, b3, acc[3][slot]);
                        acc[4][slot] = fmaf(wt, b4, acc[4][slot]);
                    }
                    if (t >= 10) {                        // emit h = h0 - 10 + t
                        float mu1 = acc[0][ts], mu2 = acc[1][ts];
                        float m11 = acc[2][ts], m22 = acc[3][ts], m12 = acc[4][ts];
                        float mu1sq = mu1*mu1, mu2sq = mu2*mu2, mu12 = mu1*mu2;
                        float s1 = m11 - mu1sq, s2 = m22 - mu2sq, s12 = m12 - mu12;
                        const float C1 = 1e-4f, C2 = 9e-4f;
                        float num = (2.f*mu12 + C1) * (2.f*s12 + C2);
                        float den = (mu1sq + mu2sq + C1) * (s1 + s2 + C2) + 1e-12f;
                        float inv = __builtin_amdgcn_rcpf(den);
                        inv = inv * (2.0f - den * inv);   // 1 NR step -> ~1ulp
                        ssum = fmaf(num, inv, ssum);
                    }
#pragma unroll
                    for (int c = 0; c < 5; ++c) acc[c][ts] = 0.f;
                }

                rawRd ^= RAW_W; rawWr ^= RAW_W; po01 ^= P01_W; po4 ^= P4_W;
            }
        }
    }

    // ---- block reduction, one atomic per block ----
#pragma unroll
    for (int off = 32; off > 0; off >>= 1)
        ssum += __shfl_down(ssum, off, 64);
    __shared__ float lsum[4];
    int lane = tid & 63, wid = tid >> 6;
    if (lane == 0) lsum[wid] = ssum;
    __syncthreads();
    if (tid == 0)
        atomicAdd(out, -(lsum[0]+lsum[1]+lsum[2]+lsum[3]) * scale);
}

extern "C" void kernel_launch(void* const* d_in, const int* in_sizes, int n_in,
                              void* d_out, int out_size, void* d_ws, size_t ws_size,
                              hipStream_t stream) {
    const float* src = (const float*)d_in[0];
    const float* ref = (const float*)d_in[1];
    float* out = (float*)d_out;

    Wts wts;
    {
        double g[KS], s = 0.0;
        for (int i = 0; i < KS; ++i) {
            double a = (double)i - (KS - 1) / 2.0;
            g[i] = exp(-(a * a) / (2.0 * 1.5 * 1.5));
            s += g[i];
        }
        for (int i = 0; i < KS; ++i) wts.w[i] = (float)(g[i] / s);
    }

    const float scale = 1.0f / (float)NTOT;

    init_out<<<1, 64, 0, stream>>>(out);
    const int g = NBATCH * (HH/HT) * (WW/WT) * (DD/DT);   // 1000
    fused<<<g, 256, 0, stream>>>(src, ref, out, wts, scale);
}